// Round 1
// baseline (567.952 us; speedup 1.0000x reference)
//
#include <hip/hip_runtime.h>

// ---------------- problem constants ----------------
#define NLAT 1228760
#define RATE_OFF 5529600      // 2*3*921600
#define BPD_OFF 6758360
#define NB_ARM 4800           // ceil(NLAT/256)
#define LSC 13.8155f

// grid sizes: (720,1280)(360,640)(180,320)(90,160)(45,80)(23,40)(12,20)
static __device__ const int d_GOFF[8] = {0,921600,1152000,1209600,1224000,1227600,1228520,1228760};
static __device__ const int d_GW[7]   = {1280,640,320,160,80,40,20};
// x-level buffers in ws (floats). level i has (7-i) channels of GH[i]*GW[i].
static __device__ const int d_XOFF[7] = {0,6451200,7833600,8121600,8179200,8190000,8191840};

#define XP_OFF   8192080   // staging for depthwise pre-conv output (max 6*230400)
#define S1_OFF   9574480   // 6*921600
#define BSUM_OFF 15104080  // NB_ARM partial sums
// s2 reuses x0 buffer (offset 0, 6451200 >= 5529600)

// 24 causal context offsets (sorted by flat idx in the 9x9 window)
static __device__ const int d_DR[24] = {-4,-3,-3,-3,-3,-3,-2,-2,-2,-2,-2,-2,-2,-1,-1,-1,-1,-1,-1,-1, 0, 0, 0, 0};
static __device__ const int d_DC[24] = { 0,-2,-1, 0, 1, 2,-3,-2,-1, 0, 1, 2, 3,-3,-2,-1, 0, 1, 2, 3,-4,-3,-2,-1};

__device__ __forceinline__ float softround_f(float x) {
    float fl = floorf(x);
    float delta = x - fl - 0.5f;
    // 0.5*tanh(d/0.3)/tanh(0.5/0.3);  0.5/tanh(5/3) = 0.53699369
    return fl + 0.5f + 0.53699369f * tanhf(delta * (1.0f/0.3f));
}

// ---------------- 1. quantize: q = softround(lat*16), write to channel 0 of each level buffer
__global__ __launch_bounds__(256) void k_quant(
    const float* __restrict__ l0, const float* __restrict__ l1,
    const float* __restrict__ l2, const float* __restrict__ l3,
    const float* __restrict__ l4, const float* __restrict__ l5,
    const float* __restrict__ l6, float* __restrict__ ws)
{
    int t = blockIdx.x*256 + threadIdx.x;
    if (t >= NLAT) return;
    int g = 0;
    #pragma unroll
    for (int i = 1; i < 7; ++i) if (t >= d_GOFF[i]) g = i;
    int local = t - d_GOFF[g];
    const float* lp = l0;
    if      (g==1) lp=l1; else if (g==2) lp=l2; else if (g==3) lp=l3;
    else if (g==4) lp=l4; else if (g==5) lp=l5; else if (g==6) lp=l6;
    ws[d_XOFF[g] + local] = softround_f(lp[local] * 16.0f);
}

// ---------------- 2. ARM: context gather + 24->24->24->2 MLP + laplace rate
__global__ __launch_bounds__(256) void k_arm(
    const float* __restrict__ ws,
    const float* __restrict__ w0, const float* __restrict__ b0,
    const float* __restrict__ w1, const float* __restrict__ b1,
    const float* __restrict__ wo, const float* __restrict__ bo,
    float* __restrict__ out_rate, float* __restrict__ bsum)
{
    int t = blockIdx.x*256 + threadIdx.x;
    float rate = 0.0f;
    if (t < NLAT) {
        int g = 0;
        #pragma unroll
        for (int i = 1; i < 7; ++i) if (t >= d_GOFF[i]) g = i;
        int local = t - d_GOFF[g];
        int w = d_GW[g];
        int y = (int)((unsigned)local / (unsigned)w);
        int x = local - y*w;
        const float* __restrict__ q = ws + d_XOFF[g];   // channel 0 = quantized latent

        float ctx[24];
        #pragma unroll
        for (int k = 0; k < 24; ++k) {
            int yy = y + d_DR[k];
            int xx = x + d_DC[k];
            float v = 0.0f;
            if (yy >= 0 && xx >= 0 && xx < w) v = q[yy*w + xx];
            ctx[k] = v;
        }

        float h0[24];
        #pragma unroll
        for (int j = 0; j < 24; ++j) h0[j] = b0[j];
        #pragma unroll
        for (int k = 0; k < 24; ++k) {
            float c = ctx[k];
            #pragma unroll
            for (int j = 0; j < 24; ++j) h0[j] = fmaf(c, w0[k*24+j], h0[j]);
        }
        #pragma unroll
        for (int j = 0; j < 24; ++j) h0[j] = fmaxf(h0[j], 0.0f);

        float h1[24];
        #pragma unroll
        for (int j = 0; j < 24; ++j) h1[j] = b1[j];
        #pragma unroll
        for (int k = 0; k < 24; ++k) {
            float c = h0[k];
            #pragma unroll
            for (int j = 0; j < 24; ++j) h1[j] = fmaf(c, w1[k*24+j], h1[j]);
        }
        #pragma unroll
        for (int j = 0; j < 24; ++j) h1[j] = fmaxf(h1[j], 0.0f);

        float o0 = bo[0], o1 = bo[1];
        #pragma unroll
        for (int j = 0; j < 24; ++j) {
            o0 = fmaf(h1[j], wo[2*j+0], o0);
            o1 = fmaf(h1[j], wo[2*j+1], o1);
        }

        float mu = o0;
        float ls = fminf(fmaxf(o1, -LSC), LSC);
        float scale = expf(-0.5f * ls);
        float inv_s = 1.0f / scale;

        float xv = q[y*w + x];
        float a = xv + 0.5f - mu;
        float b = xv - 0.5f - mu;
        float ea = expm1f(-fabsf(a) * inv_s);
        float eb = expm1f(-fabsf(b) * inv_s);
        float sa = (float)((a > 0.0f) - (a < 0.0f));
        float sb = (float)((b > 0.0f) - (b < 0.0f));
        float proba = 0.5f * (sb*eb - sa*ea);
        proba = fmaxf(proba, 1.52587890625e-05f);   // 2^-16
        rate = -log2f(proba);
        out_rate[t] = rate;
    }

    __shared__ float sm[256];
    sm[threadIdx.x] = rate;
    __syncthreads();
    #pragma unroll
    for (int st = 128; st > 0; st >>= 1) {
        if (threadIdx.x < st) sm[threadIdx.x] += sm[threadIdx.x + st];
        __syncthreads();
    }
    if (threadIdx.x == 0) bsum[blockIdx.x] = sm[0];
}

__global__ __launch_bounds__(256) void k_reduce(const float* __restrict__ bsum, float* __restrict__ out_bpd)
{
    __shared__ float sm[256];
    float s = 0.0f;
    for (int i = threadIdx.x; i < NB_ARM; i += 256) s += bsum[i];
    sm[threadIdx.x] = s;
    __syncthreads();
    #pragma unroll
    for (int st = 128; st > 0; st >>= 1) {
        if (threadIdx.x < st) sm[threadIdx.x] += sm[threadIdx.x + st];
        __syncthreads();
    }
    if (threadIdx.x == 0) out_bpd[0] = sm[0] * (1.0f/2764800.0f);
}

// ---------------- 3a. depthwise 7x7 SAME conv (same kernel for all channels)
__global__ void k_pre(const float* __restrict__ xin, float* __restrict__ xout,
                      const float* __restrict__ k7, int h, int w)
{
    int x = blockIdx.x*blockDim.x + threadIdx.x;
    int y = blockIdx.y*blockDim.y + threadIdx.y;
    int c = blockIdx.z;
    if (x >= w || y >= h) return;
    const float* p = xin + c*h*w;
    float acc = 0.0f;
    #pragma unroll
    for (int a = 0; a < 7; ++a) {
        int yy = y + a - 3;
        if (yy < 0 || yy >= h) continue;
        #pragma unroll
        for (int b = 0; b < 7; ++b) {
            int xx = x + b - 3;
            if (xx < 0 || xx >= w) continue;
            acc = fmaf(p[yy*w + xx], k7[a*7 + b], acc);
        }
    }
    xout[c*h*w + y*w + x] = acc;
}

// ---------------- 3b. depthwise convT 8x8 stride2 VALID + crop[3:3+ht,3:3+wt]
// yc[p,q] = sum_{a,b: (p+a-4) even,(q+b-4) even} x[(p+a-4)/2,(q+b-4)/2]*k[a,b]
__global__ void k_ups(const float* __restrict__ xp, float* __restrict__ xout,
                      const float* __restrict__ k8, int h, int w, int ht, int wt)
{
    int qx = blockIdx.x*blockDim.x + threadIdx.x;
    int p  = blockIdx.y*blockDim.y + threadIdx.y;
    int c  = blockIdx.z;
    if (qx >= wt || p >= ht) return;
    const float* src = xp + c*h*w;
    float acc = 0.0f;
    #pragma unroll
    for (int a = 0; a < 8; ++a) {
        int na = p + a - 4;
        if (na & 1) continue;
        int i = na >> 1;
        if (i < 0 || i >= h) continue;
        #pragma unroll
        for (int b = 0; b < 8; ++b) {
            int nb = qx + b - 4;
            if (nb & 1) continue;
            int j = nb >> 1;
            if (j < 0 || j >= w) continue;
            acc = fmaf(src[i*w + j], k8[a*8 + b], acc);
        }
    }
    // write as channel c+1 of target level (channel 0 = dec, already written)
    xout[(c+1)*ht*wt + p*wt + qx] = acc;
}

// ---------------- 4a. fused 1x1 convs: 7 -> relu 48 -> 6
__global__ __launch_bounds__(256) void k_syn01(
    const float* __restrict__ x0,
    const float* __restrict__ w0, const float* __restrict__ b0,
    const float* __restrict__ w1, const float* __restrict__ b1,
    float* __restrict__ s1)
{
    int x = blockIdx.x*256 + threadIdx.x;   // grid.x = 5 -> 1280 exact
    int y = blockIdx.y;
    int pix = y*1280 + x;
    float in[7];
    #pragma unroll
    for (int c = 0; c < 7; ++c) in[c] = x0[c*921600 + pix];
    float h[48];
    #pragma unroll
    for (int o = 0; o < 48; ++o) {
        float a = b0[o];
        #pragma unroll
        for (int c = 0; c < 7; ++c) a = fmaf(in[c], w0[o*7 + c], a);
        h[o] = fmaxf(a, 0.0f);
    }
    #pragma unroll
    for (int o = 0; o < 6; ++o) {
        float a = b1[o];
        #pragma unroll
        for (int c = 0; c < 48; ++c) a = fmaf(h[c], w1[o*48 + c], a);
        s1[o*921600 + pix] = a;
    }
}

// ---------------- 4b. s2 = relu(conv3x3(s1)+b2 + s1)
__global__ __launch_bounds__(256) void k_s2(
    const float* __restrict__ s1,
    const float* __restrict__ w2, const float* __restrict__ b2,
    float* __restrict__ s2)
{
    int x = blockIdx.x*256 + threadIdx.x;
    int y = blockIdx.y;
    int pix = y*1280 + x;
    float acc[6];
    #pragma unroll
    for (int o = 0; o < 6; ++o) acc[o] = b2[o];
    #pragma unroll
    for (int ci = 0; ci < 6; ++ci) {
        const float* p = s1 + ci*921600;
        #pragma unroll
        for (int dy = 0; dy < 3; ++dy) {
            int yy = y + dy - 1;
            if (yy < 0 || yy >= 720) continue;
            #pragma unroll
            for (int dx = 0; dx < 3; ++dx) {
                int xx = x + dx - 1;
                if (xx < 0 || xx >= 1280) continue;
                float v = p[yy*1280 + xx];
                #pragma unroll
                for (int o = 0; o < 6; ++o)
                    acc[o] = fmaf(v, w2[(o*6 + ci)*9 + dy*3 + dx], acc[o]);
            }
        }
    }
    #pragma unroll
    for (int o = 0; o < 6; ++o)
        s2[o*921600 + pix] = fmaxf(acc[o] + s1[o*921600 + pix], 0.0f);
}

// ---------------- 4c. s3 = conv3x3(s2)+b3 + s2 ; emit mu / scale
__global__ __launch_bounds__(256) void k_s3(
    const float* __restrict__ s2,
    const float* __restrict__ w3, const float* __restrict__ b3,
    float* __restrict__ out)
{
    int x = blockIdx.x*256 + threadIdx.x;
    int y = blockIdx.y;
    int pix = y*1280 + x;
    float acc[6];
    #pragma unroll
    for (int o = 0; o < 6; ++o) acc[o] = b3[o];
    #pragma unroll
    for (int ci = 0; ci < 6; ++ci) {
        const float* p = s2 + ci*921600;
        #pragma unroll
        for (int dy = 0; dy < 3; ++dy) {
            int yy = y + dy - 1;
            if (yy < 0 || yy >= 720) continue;
            #pragma unroll
            for (int dx = 0; dx < 3; ++dx) {
                int xx = x + dx - 1;
                if (xx < 0 || xx >= 1280) continue;
                float v = p[yy*1280 + xx];
                #pragma unroll
                for (int o = 0; o < 6; ++o)
                    acc[o] = fmaf(v, w3[(o*6 + ci)*9 + dy*3 + dx], acc[o]);
            }
        }
    }
    #pragma unroll
    for (int o = 0; o < 6; ++o) {
        float v = acc[o] + s2[o*921600 + pix];
        if (o < 3) {
            out[o*921600 + pix] = v;
        } else {
            float ls = fminf(fmaxf(v, -LSC), LSC);
            out[2764800 + (o-3)*921600 + pix] = expf(-0.5f * ls);
        }
    }
}

// ---------------- host ----------------
extern "C" void kernel_launch(void* const* d_in, const int* in_sizes, int n_in,
                              void* d_out, int out_size, void* d_ws, size_t ws_size,
                              hipStream_t stream)
{
    const float* lat[7];
    for (int i = 0; i < 7; ++i) lat[i] = (const float*)d_in[i];
    const float* arm_w0  = (const float*)d_in[7];
    const float* arm_b0  = (const float*)d_in[8];
    const float* arm_w1  = (const float*)d_in[9];
    const float* arm_b1  = (const float*)d_in[10];
    const float* arm_wo  = (const float*)d_in[11];
    const float* arm_bo  = (const float*)d_in[12];
    const float* pre_k   = (const float*)d_in[13];   // (6,7,7)
    const float* ups_k   = (const float*)d_in[14];   // (6,8,8)
    const float* syn_w0  = (const float*)d_in[15];
    const float* syn_b0  = (const float*)d_in[16];
    const float* syn_w1  = (const float*)d_in[17];
    const float* syn_b1  = (const float*)d_in[18];
    const float* syn_w2  = (const float*)d_in[19];
    const float* syn_b2  = (const float*)d_in[20];
    const float* syn_w3  = (const float*)d_in[21];
    const float* syn_b3  = (const float*)d_in[22];

    float* out = (float*)d_out;
    float* ws  = (float*)d_ws;

    static const int h_GH[7]   = {720,360,180,90,45,23,12};
    static const int h_GW[7]   = {1280,640,320,160,80,40,20};
    static const int h_XOFF[7] = {0,6451200,7833600,8121600,8179200,8190000,8191840};

    // 1. quantize all latents into channel-0 slots of per-level buffers
    k_quant<<<dim3(NB_ARM), dim3(256), 0, stream>>>(
        lat[0],lat[1],lat[2],lat[3],lat[4],lat[5],lat[6], ws);

    // 2. ARM + rate + bpd
    k_arm<<<dim3(NB_ARM), dim3(256), 0, stream>>>(
        ws, arm_w0, arm_b0, arm_w1, arm_b1, arm_wo, arm_bo,
        out + RATE_OFF, ws + BSUM_OFF);
    k_reduce<<<dim3(1), dim3(256), 0, stream>>>(ws + BSUM_OFF, out + BPD_OFF);

    // 3. upsampling chain: step s: level (6-s) -> level (5-s)
    for (int s = 0; s < 6; ++s) {
        int il = 6 - s, ol = 5 - s;
        int ch = s + 1;
        int h = h_GH[il], w = h_GW[il];
        int ht = h_GH[ol], wt = h_GW[ol];
        dim3 blk(32, 8);
        dim3 g1((w + 31)/32, (h + 7)/8, ch);
        k_pre<<<g1, blk, 0, stream>>>(ws + h_XOFF[il], ws + XP_OFF, pre_k + s*49, h, w);
        dim3 g2((wt + 31)/32, (ht + 7)/8, ch);
        k_ups<<<g2, blk, 0, stream>>>(ws + XP_OFF, ws + h_XOFF[ol], ups_k + s*64, h, w, ht, wt);
    }

    // 4. synthesis
    k_syn01<<<dim3(5, 720), dim3(256), 0, stream>>>(
        ws + 0, syn_w0, syn_b0, syn_w1, syn_b1, ws + S1_OFF);
    k_s2<<<dim3(5, 720), dim3(256), 0, stream>>>(
        ws + S1_OFF, syn_w2, syn_b2, ws + 0);         // s2 reuses x0 buffer
    k_s3<<<dim3(5, 720), dim3(256), 0, stream>>>(
        ws + 0, syn_w3, syn_b3, out);
}

// Round 2
// 339.013 us; speedup vs baseline: 1.6753x; 1.6753x over previous
//
#include <hip/hip_runtime.h>

// ---------------- problem constants ----------------
#define NLAT 1228760
#define RATE_OFF 5529600      // 2*3*921600
#define BPD_OFF 6758360
#define NB_ARM 4800           // ceil(NLAT/256)
#define LSC 13.8155f

// grid sizes: (720,1280)(360,640)(180,320)(90,160)(45,80)(23,40)(12,20)
static __device__ const int d_GOFF[8] = {0,921600,1152000,1209600,1224000,1227600,1228520,1228760};
static __device__ const int d_GW[7]   = {1280,640,320,160,80,40,20};
// x-level buffers in ws (floats). level i has (7-i) channels of GH[i]*GW[i].
static __device__ const int d_XOFF[7] = {0,6451200,7833600,8121600,8179200,8190000,8191840};

#define XP_OFF   8192080   // staging for depthwise pre-conv output (max 6*230400)
#define S1_OFF   9574480   // 6*921600
#define BSUM_OFF 15104080  // NB_ARM partial sums
// s2 reuses x0 buffer (offset 0, 6451200 >= 5529600)

// 24 causal context offsets (sorted by flat idx in the 9x9 window)
static __device__ const int d_DR[24] = {-4,-3,-3,-3,-3,-3,-2,-2,-2,-2,-2,-2,-2,-1,-1,-1,-1,-1,-1,-1, 0, 0, 0, 0};
static __device__ const int d_DC[24] = { 0,-2,-1, 0, 1, 2,-3,-2,-1, 0, 1, 2, 3,-3,-2,-1, 0, 1, 2, 3,-4,-3,-2,-1};

__device__ __forceinline__ float softround_f(float x) {
    float fl = floorf(x);
    float delta = x - fl - 0.5f;
    return fl + 0.5f + 0.53699369f * tanhf(delta * (1.0f/0.3f));
}

// ---------------- 1. quantize ----------------
__global__ __launch_bounds__(256) void k_quant(
    const float* __restrict__ l0, const float* __restrict__ l1,
    const float* __restrict__ l2, const float* __restrict__ l3,
    const float* __restrict__ l4, const float* __restrict__ l5,
    const float* __restrict__ l6, float* __restrict__ ws)
{
    int t = blockIdx.x*256 + threadIdx.x;
    if (t >= NLAT) return;
    int g = 0;
    #pragma unroll
    for (int i = 1; i < 7; ++i) if (t >= d_GOFF[i]) g = i;
    int local = t - d_GOFF[g];
    const float* lp = l0;
    if      (g==1) lp=l1; else if (g==2) lp=l2; else if (g==3) lp=l3;
    else if (g==4) lp=l4; else if (g==5) lp=l5; else if (g==6) lp=l6;
    ws[d_XOFF[g] + local] = softround_f(lp[local] * 16.0f);
}

// ---------------- 2. ARM ----------------
__global__ __launch_bounds__(256) void k_arm(
    const float* __restrict__ ws,
    const float* __restrict__ w0, const float* __restrict__ b0,
    const float* __restrict__ w1, const float* __restrict__ b1,
    const float* __restrict__ wo, const float* __restrict__ bo,
    float* __restrict__ out_rate, float* __restrict__ bsum)
{
    int t = blockIdx.x*256 + threadIdx.x;
    float rate = 0.0f;
    if (t < NLAT) {
        int g = 0;
        #pragma unroll
        for (int i = 1; i < 7; ++i) if (t >= d_GOFF[i]) g = i;
        int local = t - d_GOFF[g];
        int w = d_GW[g];
        int y = (int)((unsigned)local / (unsigned)w);
        int x = local - y*w;
        const float* __restrict__ q = ws + d_XOFF[g];

        float ctx[24];
        #pragma unroll
        for (int k = 0; k < 24; ++k) {
            int yy = y + d_DR[k];
            int xx = x + d_DC[k];
            float v = 0.0f;
            if (yy >= 0 && xx >= 0 && xx < w) v = q[yy*w + xx];
            ctx[k] = v;
        }

        float h0[24];
        #pragma unroll
        for (int j = 0; j < 24; ++j) h0[j] = b0[j];
        #pragma unroll
        for (int k = 0; k < 24; ++k) {
            float c = ctx[k];
            #pragma unroll
            for (int j = 0; j < 24; ++j) h0[j] = fmaf(c, w0[k*24+j], h0[j]);
        }
        #pragma unroll
        for (int j = 0; j < 24; ++j) h0[j] = fmaxf(h0[j], 0.0f);

        float h1[24];
        #pragma unroll
        for (int j = 0; j < 24; ++j) h1[j] = b1[j];
        #pragma unroll
        for (int k = 0; k < 24; ++k) {
            float c = h0[k];
            #pragma unroll
            for (int j = 0; j < 24; ++j) h1[j] = fmaf(c, w1[k*24+j], h1[j]);
        }
        #pragma unroll
        for (int j = 0; j < 24; ++j) h1[j] = fmaxf(h1[j], 0.0f);

        float o0 = bo[0], o1 = bo[1];
        #pragma unroll
        for (int j = 0; j < 24; ++j) {
            o0 = fmaf(h1[j], wo[2*j+0], o0);
            o1 = fmaf(h1[j], wo[2*j+1], o1);
        }

        float mu = o0;
        float ls = fminf(fmaxf(o1, -LSC), LSC);
        float inv_s = expf(0.5f * ls);

        float xv = q[y*w + x];
        float a = xv + 0.5f - mu;
        float b = xv - 0.5f - mu;
        float ea = expm1f(-fabsf(a) * inv_s);
        float eb = expm1f(-fabsf(b) * inv_s);
        float sa = (float)((a > 0.0f) - (a < 0.0f));
        float sb = (float)((b > 0.0f) - (b < 0.0f));
        float proba = 0.5f * (sb*eb - sa*ea);
        proba = fmaxf(proba, 1.52587890625e-05f);
        rate = -log2f(proba);
        out_rate[t] = rate;
    }

    __shared__ float sm[256];
    sm[threadIdx.x] = rate;
    __syncthreads();
    #pragma unroll
    for (int st = 128; st > 0; st >>= 1) {
        if (threadIdx.x < st) sm[threadIdx.x] += sm[threadIdx.x + st];
        __syncthreads();
    }
    if (threadIdx.x == 0) bsum[blockIdx.x] = sm[0];
}

__global__ __launch_bounds__(256) void k_reduce(const float* __restrict__ bsum, float* __restrict__ out_bpd)
{
    __shared__ float sm[256];
    float s = 0.0f;
    for (int i = threadIdx.x; i < NB_ARM; i += 256) s += bsum[i];
    sm[threadIdx.x] = s;
    __syncthreads();
    #pragma unroll
    for (int st = 128; st > 0; st >>= 1) {
        if (threadIdx.x < st) sm[threadIdx.x] += sm[threadIdx.x + st];
        __syncthreads();
    }
    if (threadIdx.x == 0) out_bpd[0] = sm[0] * (1.0f/2764800.0f);
}

// ---------------- 3a. depthwise 7x7 SAME conv, interior fast path ----------------
__global__ void k_pre(const float* __restrict__ xin, float* __restrict__ xout,
                      const float* __restrict__ k7, int h, int w)
{
    int x = blockIdx.x*blockDim.x + threadIdx.x;
    int y = blockIdx.y*blockDim.y + threadIdx.y;
    int c = blockIdx.z;
    if (x >= w || y >= h) return;
    const float* p = xin + c*h*w;
    float acc = 0.0f;
    if (x >= 3 && x < w-3 && y >= 3 && y < h-3) {
        const float* q = p + (y-3)*w + (x-3);
        #pragma unroll
        for (int a = 0; a < 7; ++a)
            #pragma unroll
            for (int b = 0; b < 7; ++b)
                acc = fmaf(q[a*w + b], k7[a*7 + b], acc);
    } else {
        #pragma unroll
        for (int a = 0; a < 7; ++a) {
            int yy = y + a - 3;
            if (yy < 0 || yy >= h) continue;
            #pragma unroll
            for (int b = 0; b < 7; ++b) {
                int xx = x + b - 3;
                if (xx < 0 || xx >= w) continue;
                acc = fmaf(p[yy*w + xx], k7[a*7 + b], acc);
            }
        }
    }
    xout[c*h*w + y*w + x] = acc;
}

// ---------------- 3b. convT 8x8 stride2: 2x2 outputs per thread ----------------
// full formula (verified R1): y[p,q] = sum_{a,b: (p+a-4)even,(q+b-4)even} x[(p+a-4)/2][(q+b-4)/2]*k[a,b]
// parity pp=p&1 -> a=pp+2t; input row i = p' + pp + t - 2 where p=2p'+pp.
__global__ void k_ups2(const float* __restrict__ xp, float* __restrict__ xout,
                       const float* __restrict__ k8, int h, int w, int ht, int wt)
{
    int qb = blockIdx.x*blockDim.x + threadIdx.x;   // q' (input-aligned col)
    int pb = blockIdx.y*blockDim.y + threadIdx.y;   // p' (input-aligned row)
    int c  = blockIdx.z;
    int hb = (ht + 1) >> 1, wb = (wt + 1) >> 1;
    if (qb >= wb || pb >= hb) return;
    const float* __restrict__ src = xp + c*h*w;

    float in[5][5];
    #pragma unroll
    for (int r = 0; r < 5; ++r) {
        int i = pb - 2 + r;
        bool rv = (i >= 0) && (i < h);
        #pragma unroll
        for (int s = 0; s < 5; ++s) {
            int j = qb - 2 + s;
            in[r][s] = (rv && j >= 0 && j < w) ? src[i*w + j] : 0.0f;
        }
    }

    float* __restrict__ dst = xout + (c+1)*ht*wt;
    #pragma unroll
    for (int pp = 0; pp < 2; ++pp) {
        int p = 2*pb + pp;
        if (p >= ht) break;
        #pragma unroll
        for (int qq = 0; qq < 2; ++qq) {
            int q = 2*qb + qq;
            if (q >= wt) continue;
            float acc = 0.0f;
            #pragma unroll
            for (int t = 0; t < 4; ++t)
                #pragma unroll
                for (int u = 0; u < 4; ++u)
                    acc = fmaf(in[pp+t][qq+u], k8[(pp+2*t)*8 + (qq+2*u)], acc);
            dst[p*wt + q] = acc;
        }
    }
}

// ---------------- 4a. fused 1x1 convs: 7 -> relu 48 -> 6 ----------------
__global__ __launch_bounds__(256) void k_syn01(
    const float* __restrict__ x0,
    const float* __restrict__ w0, const float* __restrict__ b0,
    const float* __restrict__ w1, const float* __restrict__ b1,
    float* __restrict__ s1)
{
    int x = blockIdx.x*256 + threadIdx.x;
    int y = blockIdx.y;
    int pix = y*1280 + x;
    float in[7];
    #pragma unroll
    for (int c = 0; c < 7; ++c) in[c] = x0[c*921600 + pix];
    float h[48];
    #pragma unroll
    for (int o = 0; o < 48; ++o) {
        float a = b0[o];
        #pragma unroll
        for (int c = 0; c < 7; ++c) a = fmaf(in[c], w0[o*7 + c], a);
        h[o] = fmaxf(a, 0.0f);
    }
    #pragma unroll
    for (int o = 0; o < 6; ++o) {
        float a = b1[o];
        #pragma unroll
        for (int c = 0; c < 48; ++c) a = fmaf(h[c], w1[o*48 + c], a);
        s1[o*921600 + pix] = a;
    }
}

// ---------------- 4b. s2 = relu(conv3x3(s1)+b2 + s1) ----------------
__global__ __launch_bounds__(256) void k_s2(
    const float* __restrict__ s1,
    const float* __restrict__ w2, const float* __restrict__ b2,
    float* __restrict__ s2)
{
    int x = blockIdx.x*256 + threadIdx.x;
    int y = blockIdx.y;
    int pix = y*1280 + x;
    float acc[6];
    #pragma unroll
    for (int o = 0; o < 6; ++o) acc[o] = b2[o];
    bool interior = (x >= 1) && (x < 1279) && (y >= 1) && (y < 719);
    if (interior) {
        #pragma unroll
        for (int ci = 0; ci < 6; ++ci) {
            const float* p = s1 + ci*921600 + pix;
            #pragma unroll
            for (int dy = 0; dy < 3; ++dy)
                #pragma unroll
                for (int dx = 0; dx < 3; ++dx) {
                    float v = p[(dy-1)*1280 + dx - 1];
                    #pragma unroll
                    for (int o = 0; o < 6; ++o)
                        acc[o] = fmaf(v, w2[(o*6 + ci)*9 + dy*3 + dx], acc[o]);
                }
        }
    } else {
        #pragma unroll
        for (int ci = 0; ci < 6; ++ci) {
            const float* p = s1 + ci*921600;
            #pragma unroll
            for (int dy = 0; dy < 3; ++dy) {
                int yy = y + dy - 1;
                if (yy < 0 || yy >= 720) continue;
                #pragma unroll
                for (int dx = 0; dx < 3; ++dx) {
                    int xx = x + dx - 1;
                    if (xx < 0 || xx >= 1280) continue;
                    float v = p[yy*1280 + xx];
                    #pragma unroll
                    for (int o = 0; o < 6; ++o)
                        acc[o] = fmaf(v, w2[(o*6 + ci)*9 + dy*3 + dx], acc[o]);
                }
            }
        }
    }
    #pragma unroll
    for (int o = 0; o < 6; ++o)
        s2[o*921600 + pix] = fmaxf(acc[o] + s1[o*921600 + pix], 0.0f);
}

// ---------------- 4c. s3 = conv3x3(s2)+b3 + s2 ; emit mu / scale ----------------
__global__ __launch_bounds__(256) void k_s3(
    const float* __restrict__ s2,
    const float* __restrict__ w3, const float* __restrict__ b3,
    float* __restrict__ out)
{
    int x = blockIdx.x*256 + threadIdx.x;
    int y = blockIdx.y;
    int pix = y*1280 + x;
    float acc[6];
    #pragma unroll
    for (int o = 0; o < 6; ++o) acc[o] = b3[o];
    bool interior = (x >= 1) && (x < 1279) && (y >= 1) && (y < 719);
    if (interior) {
        #pragma unroll
        for (int ci = 0; ci < 6; ++ci) {
            const float* p = s2 + ci*921600 + pix;
            #pragma unroll
            for (int dy = 0; dy < 3; ++dy)
                #pragma unroll
                for (int dx = 0; dx < 3; ++dx) {
                    float v = p[(dy-1)*1280 + dx - 1];
                    #pragma unroll
                    for (int o = 0; o < 6; ++o)
                        acc[o] = fmaf(v, w3[(o*6 + ci)*9 + dy*3 + dx], acc[o]);
                }
        }
    } else {
        #pragma unroll
        for (int ci = 0; ci < 6; ++ci) {
            const float* p = s2 + ci*921600;
            #pragma unroll
            for (int dy = 0; dy < 3; ++dy) {
                int yy = y + dy - 1;
                if (yy < 0 || yy >= 720) continue;
                #pragma unroll
                for (int dx = 0; dx < 3; ++dx) {
                    int xx = x + dx - 1;
                    if (xx < 0 || xx >= 1280) continue;
                    float v = p[yy*1280 + xx];
                    #pragma unroll
                    for (int o = 0; o < 6; ++o)
                        acc[o] = fmaf(v, w3[(o*6 + ci)*9 + dy*3 + dx], acc[o]);
                }
            }
        }
    }
    #pragma unroll
    for (int o = 0; o < 6; ++o) {
        float v = acc[o] + s2[o*921600 + pix];
        if (o < 3) {
            out[o*921600 + pix] = v;
        } else {
            float ls = fminf(fmaxf(v, -LSC), LSC);
            out[2764800 + (o-3)*921600 + pix] = expf(-0.5f * ls);
        }
    }
}

// ---------------- host ----------------
extern "C" void kernel_launch(void* const* d_in, const int* in_sizes, int n_in,
                              void* d_out, int out_size, void* d_ws, size_t ws_size,
                              hipStream_t stream)
{
    const float* lat[7];
    for (int i = 0; i < 7; ++i) lat[i] = (const float*)d_in[i];
    const float* arm_w0  = (const float*)d_in[7];
    const float* arm_b0  = (const float*)d_in[8];
    const float* arm_w1  = (const float*)d_in[9];
    const float* arm_b1  = (const float*)d_in[10];
    const float* arm_wo  = (const float*)d_in[11];
    const float* arm_bo  = (const float*)d_in[12];
    const float* pre_k   = (const float*)d_in[13];
    const float* ups_k   = (const float*)d_in[14];
    const float* syn_w0  = (const float*)d_in[15];
    const float* syn_b0  = (const float*)d_in[16];
    const float* syn_w1  = (const float*)d_in[17];
    const float* syn_b1  = (const float*)d_in[18];
    const float* syn_w2  = (const float*)d_in[19];
    const float* syn_b2  = (const float*)d_in[20];
    const float* syn_w3  = (const float*)d_in[21];
    const float* syn_b3  = (const float*)d_in[22];

    float* out = (float*)d_out;
    float* ws  = (float*)d_ws;

    static const int h_GH[7]   = {720,360,180,90,45,23,12};
    static const int h_GW[7]   = {1280,640,320,160,80,40,20};
    static const int h_XOFF[7] = {0,6451200,7833600,8121600,8179200,8190000,8191840};

    k_quant<<<dim3(NB_ARM), dim3(256), 0, stream>>>(
        lat[0],lat[1],lat[2],lat[3],lat[4],lat[5],lat[6], ws);

    k_arm<<<dim3(NB_ARM), dim3(256), 0, stream>>>(
        ws, arm_w0, arm_b0, arm_w1, arm_b1, arm_wo, arm_bo,
        out + RATE_OFF, ws + BSUM_OFF);
    k_reduce<<<dim3(1), dim3(256), 0, stream>>>(ws + BSUM_OFF, out + BPD_OFF);

    for (int s = 0; s < 6; ++s) {
        int il = 6 - s, ol = 5 - s;
        int ch = s + 1;
        int h = h_GH[il], w = h_GW[il];
        int ht = h_GH[ol], wt = h_GW[ol];
        dim3 blk(32, 8);
        dim3 g1((w + 31)/32, (h + 7)/8, ch);
        k_pre<<<g1, blk, 0, stream>>>(ws + h_XOFF[il], ws + XP_OFF, pre_k + s*49, h, w);
        int hb = (ht + 1) / 2, wb = (wt + 1) / 2;
        dim3 g2((wb + 31)/32, (hb + 7)/8, ch);
        k_ups2<<<g2, blk, 0, stream>>>(ws + XP_OFF, ws + h_XOFF[ol], ups_k + s*64, h, w, ht, wt);
    }

    k_syn01<<<dim3(5, 720), dim3(256), 0, stream>>>(
        ws + 0, syn_w0, syn_b0, syn_w1, syn_b1, ws + S1_OFF);
    k_s2<<<dim3(5, 720), dim3(256), 0, stream>>>(
        ws + S1_OFF, syn_w2, syn_b2, ws + 0);
    k_s3<<<dim3(5, 720), dim3(256), 0, stream>>>(
        ws + 0, syn_w3, syn_b3, out);
}